// Round 20
// baseline (117.976 us; speedup 1.0000x reference)
//
#include <hip/hip_runtime.h>

#define EPS 1e-6f

typedef __attribute__((ext_vector_type(8))) short short8;   // 8 x bf16 bits
typedef __attribute__((ext_vector_type(16))) float f32x16;  // MFMA 32x32 acc
typedef __attribute__((ext_vector_type(2))) unsigned int uint2v;

__device__ __forceinline__ float elu1(float x) {
    // elu(x) + 1  ==  x > 0 ? x + 1 : exp(x)
    return x > 0.f ? x + 1.f : __expf(x);
}

// fp32 -> bf16 bits (low 16), round-to-nearest-even
__device__ __forceinline__ unsigned f2bfu(float x) {
    unsigned u = __float_as_uint(x);
    return (u + 0x7FFFu + ((u >> 16) & 1u)) >> 16;
}

__device__ __forceinline__ float fidx(const float4& v, int i) {
    return i == 0 ? v.x : i == 1 ? v.y : i == 2 ? v.z : v.w;  // i compile-time
}

#define LGKMCNT0() asm volatile("s_waitcnt lgkmcnt(0)" ::: "memory")
// raw barrier: does NOT drain vmcnt, so global loads stay in flight.
#define BAR() do { LGKMCNT0(); __builtin_amdgcn_s_barrier(); \
                   asm volatile("" ::: "memory"); } while (0)

// ---------------------------------------------------------------------------
// Phase 1 (R20 = R17 + occupancy): R17 verbatim except (a) tail combine uses
// ONE 16KB buffer in 2 phases over td (LDS 52.2 -> 35.8 KB) and (b)
// __launch_bounds__(256,4) -> 4 blocks/CU (was 2). Rationale: R15 probe =
// skeleton 19us; R17 (light compute) and R18 (heavy compute) both = ~60us ->
// stage and compute phases serialize within a block; at 2 blocks/CU there
// is no cross-block overlap. 4 blocks/CU lets one block's compute cover
// another's staging latency.
// s' = 4*r0 + k permuted-s transposed bf16 layout (R17, verified):
//   staging: 1 ds_write_b64 per d (8/thread/iter)
//   fragments: 2 ds_read_b64 per fragment, 8/iter, independent
// Fragment mapping (verified R5-R17): A row d=l&31(+32td), k=(l>>5)*8+j;
// B col m=l&31(+32tm); C/D col=l&31, row=(r&3)+8*(r>>2)+4*(l>>5).
// ---------------------------------------------------------------------------
template<int ITERS>
__global__ __launch_bounds__(256, 4) void kv_partial_kernel(
    const float* __restrict__ keys, const float* __restrict__ values,
    const float* __restrict__ mask, float* __restrict__ pkv,
    float* __restrict__ pks)
{
    __shared__ __align__(16) unsigned short KVbt[2][64][68];  // K, V: 17.4 KB
    __shared__ float cmb[4096];      // 16 KB: ksum stage + combine buffer
    __shared__ float Mls[ITERS * 64];

    const int nh = blockIdx.x, n = nh >> 4, h = nh & 15;
    const int chunk = blockIdx.y;
    const int t = threadIdx.x, wv = t >> 6, l = t & 63;
    const int half = l >> 5, col = l & 31;
    const int r0 = t >> 4, c4 = (t & 15) * 4;   // staging role

    const int s0 = chunk * (ITERS * 64);
    const float* kb = keys   + ((size_t)(n * 4096 + s0) * 16 + h) * 64;
    const float* vb = values + ((size_t)(n * 4096 + s0) * 16 + h) * 64;

    if (t < ITERS * 16)
        *(float4*)&Mls[t * 4] = *(const float4*)(mask + n * 4096 + s0 + t * 4);

    char* kvbase = (char*)&KVbt[0][0][0];
    // per-lane fragment read base: row d=col, byte col*136 + 32wv + 16half
    const char* lbase = kvbase + col * 136 + 32 * wv + 16 * half;

    f32x16 acc[2][2];
    #pragma unroll
    for (int a = 0; a < 2; ++a)
        #pragma unroll
        for (int b = 0; b < 2; ++b)
            #pragma unroll
            for (int r = 0; r < 16; ++r) acc[a][b][r] = 0.f;
    float4 ks4 = make_float4(0.f, 0.f, 0.f, 0.f);

    float4 kr[4], vr[4];
    #pragma unroll
    for (int k = 0; k < 4; ++k) {     // prologue: tile 0 (8 float4/thread)
        const size_t go = (size_t)(r0 + 16 * k) * 1024 + c4;
        kr[k] = *(const float4*)(kb + go);
        vr[k] = *(const float4*)(vb + go);
    }

    #pragma unroll
    for (int it = 0; it < ITERS; ++it) {
        BAR();   // (A) prior tile's fragment reads done; Mls visible at it==0
        // transform all 4 rows (fp32), then pack transposed bf16 writes
        float4 kt[4];
        #pragma unroll
        for (int k = 0; k < 4; ++k) {
            const float msk = Mls[it * 64 + r0 + 16 * k];
            float4 kk = kr[k];
            kk.x = elu1(kk.x) * msk; kk.y = elu1(kk.y) * msk;
            kk.z = elu1(kk.z) * msk; kk.w = elu1(kk.w) * msk;
            ks4.x += kk.x; ks4.y += kk.y; ks4.z += kk.z; ks4.w += kk.w;
            kt[k] = kk;
        }
        #pragma unroll
        for (int i = 0; i < 4; ++i) {     // d = c4+i; s' = 4*r0 + k
            uint2v kw, vw;
            kw[0] = f2bfu(fidx(kt[0], i)) | (f2bfu(fidx(kt[1], i)) << 16);
            kw[1] = f2bfu(fidx(kt[2], i)) | (f2bfu(fidx(kt[3], i)) << 16);
            vw[0] = f2bfu(fidx(vr[0], i)) | (f2bfu(fidx(vr[1], i)) << 16);
            vw[1] = f2bfu(fidx(vr[2], i)) | (f2bfu(fidx(vr[3], i)) << 16);
            const int bo = (c4 + i) * 136 + 8 * r0;
            *(uint2v*)(kvbase + bo) = kw;            // K row d
            *(uint2v*)(kvbase + 8704 + bo) = vw;     // V row d
        }
        BAR();   // (B) bf16 tiles staged & visible
        if (it + 1 < ITERS) {          // issue next tile; stays in flight
            #pragma unroll
            for (int k = 0; k < 4; ++k) {
                const size_t go = (size_t)(r0 + 16 * k + 64 * (it + 1)) * 1024 + c4;
                kr[k] = *(const float4*)(kb + go);
                vr[k] = *(const float4*)(vb + go);
            }
        }
        // fragment assembly: 8 independent ds_read_b64
        union UF { uint2v u[2]; short8 s; };
        UF ua, ub, uc, ud;
        ua.u[0] = *(const uint2v*)(lbase + 0);        // ka0 (d=col)
        ua.u[1] = *(const uint2v*)(lbase + 8);
        ub.u[0] = *(const uint2v*)(lbase + 4352);     // ka1 (d=col+32)
        ub.u[1] = *(const uint2v*)(lbase + 4360);
        uc.u[0] = *(const uint2v*)(lbase + 8704);     // va0 (m=col)
        uc.u[1] = *(const uint2v*)(lbase + 8712);
        ud.u[0] = *(const uint2v*)(lbase + 13056);    // va1 (m=col+32)
        ud.u[1] = *(const uint2v*)(lbase + 13064);
        acc[0][0] = __builtin_amdgcn_mfma_f32_32x32x16_bf16(ua.s, uc.s, acc[0][0], 0, 0, 0);
        acc[0][1] = __builtin_amdgcn_mfma_f32_32x32x16_bf16(ua.s, ud.s, acc[0][1], 0, 0, 0);
        acc[1][0] = __builtin_amdgcn_mfma_f32_32x32x16_bf16(ub.s, uc.s, acc[1][0], 0, 0, 0);
        acc[1][1] = __builtin_amdgcn_mfma_f32_32x32x16_bf16(ub.s, ud.s, acc[1][1], 0, 0, 0);
    }

    // ---- ksum block reduce (thread covered cols c4..c4+3 of its rows)
    BAR();
    *(float4*)&cmb[r0 * 64 + c4] = ks4;
    BAR();
    if (t < 64) {
        float s = 0.f;
        #pragma unroll
        for (int r = 0; r < 16; ++r) s += cmb[r * 64 + t];
        pks[((size_t)chunk * 64 + nh) * 64 + t] = s;
    }

    // ---- acc tree-combine: 2 phases over td, ONE 16KB buffer
    float* pb = pkv + ((size_t)chunk * 64 + nh) * 4096;
#define FW(BUF, TD)                                                        \
    { _Pragma("unroll") for (int tm = 0; tm < 2; ++tm)                     \
      _Pragma("unroll") for (int r = 0; r < 16; ++r)                       \
          (BUF)[(tm * 16 + r) * 64 + l] = acc[TD][tm][r]; }
#define FR(BUF, TD)                                                        \
    { _Pragma("unroll") for (int tm = 0; tm < 2; ++tm)                     \
      _Pragma("unroll") for (int r = 0; r < 16; ++r)                       \
          acc[TD][tm][r] += (BUF)[(tm * 16 + r) * 64 + l]; }
    #pragma unroll
    for (int td = 0; td < 2; ++td) {
        BAR();   // prior phase's reads (or ksum reads) done
        if (wv == 2) FW(&cmb[0], td);
        if (wv == 3) FW(&cmb[2048], td);
        BAR();
        if (wv == 0) FR(&cmb[0], td);
        if (wv == 1) FR(&cmb[2048], td);
        BAR();
        if (wv == 1) FW(&cmb[0], td);
        BAR();
        if (wv == 0) {
            FR(&cmb[0], td);
            #pragma unroll
            for (int tm = 0; tm < 2; ++tm)
                #pragma unroll
                for (int r = 0; r < 16; ++r) {
                    const int d = 32 * td + (r & 3) + 8 * (r >> 2) + 4 * half;
                    pb[(size_t)d * 64 + 32 * tm + col] = acc[td][tm][r];
                }
        }
    }
#undef FW
#undef FR
}

// ---------------------------------------------------------------------------
// Reduce: kvt[nh][d][m] = sum_c pkv[c][nh][d][m];  ksum[nh][d] = sum_c pks.
// (pkv already in final [d][m] order -> contiguous float4 writes.)
// ---------------------------------------------------------------------------
__global__ __launch_bounds__(256) void kv_reduce_kernel(
    const float* __restrict__ pkv, const float* __restrict__ pks,
    float* __restrict__ kvt, float* __restrict__ ksum, int CH)
{
    const int nh = blockIdx.x;
    const int f4 = blockIdx.y * 256 + threadIdx.x;   // float4 slot 0..1023
    float4 s4 = make_float4(0.f, 0.f, 0.f, 0.f);
    #pragma unroll 4
    for (int c = 0; c < CH; ++c) {
        const float4 v = *(const float4*)(pkv + ((size_t)c * 64 + nh) * 4096 + f4 * 4);
        s4.x += v.x; s4.y += v.y; s4.z += v.z; s4.w += v.w;
    }
    *(float4*)(kvt + (size_t)nh * 4096 + f4 * 4) = s4;

    if (blockIdx.y == 0 && threadIdx.x < 64) {
        float s = 0.f;
        #pragma unroll 4
        for (int c = 0; c < CH; ++c)
            s += pks[((size_t)c * 64 + nh) * 64 + threadIdx.x];
        ksum[nh * 64 + threadIdx.x] = s;
    }
}

// ---------------------------------------------------------------------------
// Phase 2: out[n,l,h,m] = z_l * sum_d Q'[l,d] * KVT[d,m],
//          z_l = 1/(sum_d Q'[l,d]*Ksum[d] + EPS)   (R8 version, ~floor)
// ---------------------------------------------------------------------------
__global__ __launch_bounds__(256) void out_kernel(
    const float* __restrict__ queries, const float* __restrict__ kvt,
    const float* __restrict__ ksum, float* __restrict__ out)
{
    __shared__ float Qs[64][68];    // [l][d]
    __shared__ float KVs[64][68];   // [d][m]
    __shared__ float Ksm[64];

    const int nh = blockIdx.x;
    const int n = nh >> 4, h = nh & 15;
    const int t = threadIdx.x;
    const int l0 = blockIdx.y * 64;

    #pragma unroll
    for (int k = 0; k < 4; ++k) {
        const int idx = t + k * 256;
        *(float4*)&KVs[idx >> 4][(idx & 15) * 4] =
            *(const float4*)(kvt + (size_t)nh * 4096 + idx * 4);
    }
    if (t < 64) Ksm[t] = ksum[nh * 64 + t];

    #pragma unroll
    for (int k = 0; k < 4; ++k) {
        const int idx = t + k * 256;
        const int row = idx >> 4, seg = idx & 15;
        const size_t g = ((size_t)(n * 4096 + l0 + row) * 16 + h) * 64 + seg * 4;
        float4 q4 = *(const float4*)(queries + g);
        q4.x = elu1(q4.x);
        q4.y = elu1(q4.y);
        q4.z = elu1(q4.z);
        q4.w = elu1(q4.w);
        *(float4*)&Qs[row][seg * 4] = q4;
    }
    __syncthreads();

    const int mg = t & 7;          // m cols 4mg..+3 and 32+4mg..+3
    const int lg = t >> 3;         // 0..31; rows lg, lg+32

    float acc[2][8];
    float zacc[2] = {0.f, 0.f};
    #pragma unroll
    for (int i = 0; i < 2; ++i)
        #pragma unroll
        for (int j = 0; j < 8; ++j) acc[i][j] = 0.f;

    #pragma unroll 4
    for (int d0 = 0; d0 < 64; d0 += 4) {
        const float4 km4 = *(const float4*)&Ksm[d0];
        float4 q[2];
        q[0] = *(const float4*)&Qs[lg][d0];
        q[1] = *(const float4*)&Qs[lg + 32][d0];
        #pragma unroll
        for (int i = 0; i < 2; ++i)
            zacc[i] += q[i].x * km4.x + q[i].y * km4.y +
                       q[i].z * km4.z + q[i].w * km4.w;
        #pragma unroll
        for (int r = 0; r < 4; ++r) {
            const float4 kva = *(const float4*)&KVs[d0 + r][mg * 4];
            const float4 kvb = *(const float4*)&KVs[d0 + r][32 + mg * 4];
            #pragma unroll
            for (int i = 0; i < 2; ++i) {
                const float qc = fidx(q[i], r);
                acc[i][0] = fmaf(qc, kva.x, acc[i][0]);
                acc[i][1] = fmaf(qc, kva.y, acc[i][1]);
                acc[i][2] = fmaf(qc, kva.z, acc[i][2]);
                acc[i][3] = fmaf(qc, kva.w, acc[i][3]);
                acc[i][4] = fmaf(qc, kvb.x, acc[i][4]);
                acc[i][5] = fmaf(qc, kvb.y, acc[i][5]);
                acc[i][6] = fmaf(qc, kvb.z, acc[i][6]);
                acc[i][7] = fmaf(qc, kvb.w, acc[i][7]);
            }
        }
    }

    #pragma unroll
    for (int i = 0; i < 2; ++i) {
        const float z = 1.f / (zacc[i] + EPS);
        const int row = l0 + lg + 32 * i;
        const size_t g = ((size_t)(n * 4096 + row) * 16 + h) * 64;
        float4 o;
        o.x = acc[i][0] * z; o.y = acc[i][1] * z;
        o.z = acc[i][2] * z; o.w = acc[i][3] * z;
        *(float4*)(out + g + mg * 4) = o;
        o.x = acc[i][4] * z; o.y = acc[i][5] * z;
        o.z = acc[i][6] * z; o.w = acc[i][7] * z;
        *(float4*)(out + g + 32 + mg * 4) = o;
    }
}

extern "C" void kernel_launch(void* const* d_in, const int* in_sizes, int n_in,
                              void* d_out, int out_size, void* d_ws, size_t ws_size,
                              hipStream_t stream) {
    const float* queries = (const float*)d_in[0];
    const float* keys    = (const float*)d_in[1];
    const float* values  = (const float*)d_in[2];
    const float* mask    = (const float*)d_in[3];
    float* out = (float*)d_out;

    const int CH = 8;   // ~9MB workspace (fits; R1 used 18MB)

    float* pkv  = (float*)d_ws;                      // [8][64][4096] (d,m)
    float* pks  = pkv + (size_t)CH * 64 * 4096;      // [8][64][64]
    float* kvt  = pks + (size_t)CH * 64 * 64;        // [64][4096]
    float* ksum = kvt + (size_t)64 * 4096;           // [64][64]

    kv_partial_kernel<8><<<dim3(64, CH), 256, 0, stream>>>(keys, values, mask,
                                                           pkv, pks);
    kv_reduce_kernel<<<dim3(64, 4), 256, 0, stream>>>(pkv, pks, kvt, ksum, CH);
    out_kernel<<<dim3(64, 64), 256, 0, stream>>>(queries, kvt, ksum, out);
}

// Round 21
// 75.232 us; speedup vs baseline: 1.5681x; 1.5681x over previous
//
#include <hip/hip_runtime.h>

#define EPS 1e-6f

typedef __attribute__((ext_vector_type(8))) short short8;   // 8 x bf16 bits
typedef __attribute__((ext_vector_type(16))) float f32x16;  // MFMA 32x32 acc
typedef __attribute__((ext_vector_type(2))) unsigned int uint2v;

__device__ __forceinline__ float elu1(float x) {
    // elu(x) + 1  ==  x > 0 ? x + 1 : exp(x)
    return x > 0.f ? x + 1.f : __expf(x);
}

// fp32 -> bf16 bits (low 16), round-to-nearest-even
__device__ __forceinline__ unsigned f2bfu(float x) {
    unsigned u = __float_as_uint(x);
    return (u + 0x7FFFu + ((u >> 16) & 1u)) >> 16;
}

__device__ __forceinline__ float fidx(const float4& v, int i) {
    return i == 0 ? v.x : i == 1 ? v.y : i == 2 ? v.z : v.w;  // i compile-time
}

#define LGKMCNT0() asm volatile("s_waitcnt lgkmcnt(0)" ::: "memory")
// raw barrier: does NOT drain vmcnt, so global loads stay in flight.
#define BAR() do { LGKMCNT0(); __builtin_amdgcn_s_barrier(); \
                   asm volatile("" ::: "memory"); } while (0)

// ---------------------------------------------------------------------------
// Phase 1 (R21): R17 verbatim (VGPR=120, zero spill, best total 73.8us) +
// R20's correctness-proven single-cmb tail (LDS 52.2 -> 35.8 KB), with
// launch_bounds kept at (256,2) — R20's (256,4) coerced the allocator to
// VGPR=64 and spilled catastrophically (FETCH 66->109MB, WRITE 134MB).
// With 35.8 KB LDS and VGPR<=128 the HARDWARE can co-schedule 4 blocks/CU
// (was 3, LDS-limited): cross-block overlap of staging latency vs MFMA
// phase — the overlap R15's probe showed is missing (19us skeleton + ~40us
// compute currently serialize within each block).
// s' = 4*r0 + k permuted-s transposed bf16 layout (R17, verified):
//   staging: 1 ds_write_b64 per d (8/thread/iter)
//   fragments: 2 ds_read_b64 per fragment, 8/iter, independent
// Fragment mapping (verified R5-R17): A row d=l&31(+32td), k=(l>>5)*8+j;
// B col m=l&31(+32tm); C/D col=l&31, row=(r&3)+8*(r>>2)+4*(l>>5).
// ---------------------------------------------------------------------------
template<int ITERS>
__global__ __launch_bounds__(256, 2) void kv_partial_kernel(
    const float* __restrict__ keys, const float* __restrict__ values,
    const float* __restrict__ mask, float* __restrict__ pkv,
    float* __restrict__ pks)
{
    __shared__ __align__(16) unsigned short KVbt[2][64][68];  // K, V: 17.4 KB
    __shared__ float cmb[4096];      // 16 KB: ksum stage + combine buffer
    __shared__ float Mls[ITERS * 64];

    const int nh = blockIdx.x, n = nh >> 4, h = nh & 15;
    const int chunk = blockIdx.y;
    const int t = threadIdx.x, wv = t >> 6, l = t & 63;
    const int half = l >> 5, col = l & 31;
    const int r0 = t >> 4, c4 = (t & 15) * 4;   // staging role

    const int s0 = chunk * (ITERS * 64);
    const float* kb = keys   + ((size_t)(n * 4096 + s0) * 16 + h) * 64;
    const float* vb = values + ((size_t)(n * 4096 + s0) * 16 + h) * 64;

    if (t < ITERS * 16)
        *(float4*)&Mls[t * 4] = *(const float4*)(mask + n * 4096 + s0 + t * 4);

    char* kvbase = (char*)&KVbt[0][0][0];
    // per-lane fragment read base: row d=col, byte col*136 + 32wv + 16half
    const char* lbase = kvbase + col * 136 + 32 * wv + 16 * half;

    f32x16 acc[2][2];
    #pragma unroll
    for (int a = 0; a < 2; ++a)
        #pragma unroll
        for (int b = 0; b < 2; ++b)
            #pragma unroll
            for (int r = 0; r < 16; ++r) acc[a][b][r] = 0.f;
    float4 ks4 = make_float4(0.f, 0.f, 0.f, 0.f);

    float4 kr[4], vr[4];
    #pragma unroll
    for (int k = 0; k < 4; ++k) {     // prologue: tile 0 (8 float4/thread)
        const size_t go = (size_t)(r0 + 16 * k) * 1024 + c4;
        kr[k] = *(const float4*)(kb + go);
        vr[k] = *(const float4*)(vb + go);
    }

    #pragma unroll
    for (int it = 0; it < ITERS; ++it) {
        BAR();   // (A) prior tile's fragment reads done; Mls visible at it==0
        // transform all 4 rows (fp32), then pack transposed bf16 writes
        float4 kt[4];
        #pragma unroll
        for (int k = 0; k < 4; ++k) {
            const float msk = Mls[it * 64 + r0 + 16 * k];
            float4 kk = kr[k];
            kk.x = elu1(kk.x) * msk; kk.y = elu1(kk.y) * msk;
            kk.z = elu1(kk.z) * msk; kk.w = elu1(kk.w) * msk;
            ks4.x += kk.x; ks4.y += kk.y; ks4.z += kk.z; ks4.w += kk.w;
            kt[k] = kk;
        }
        #pragma unroll
        for (int i = 0; i < 4; ++i) {     // d = c4+i; s' = 4*r0 + k
            uint2v kw, vw;
            kw[0] = f2bfu(fidx(kt[0], i)) | (f2bfu(fidx(kt[1], i)) << 16);
            kw[1] = f2bfu(fidx(kt[2], i)) | (f2bfu(fidx(kt[3], i)) << 16);
            vw[0] = f2bfu(fidx(vr[0], i)) | (f2bfu(fidx(vr[1], i)) << 16);
            vw[1] = f2bfu(fidx(vr[2], i)) | (f2bfu(fidx(vr[3], i)) << 16);
            const int bo = (c4 + i) * 136 + 8 * r0;
            *(uint2v*)(kvbase + bo) = kw;            // K row d
            *(uint2v*)(kvbase + 8704 + bo) = vw;     // V row d
        }
        BAR();   // (B) bf16 tiles staged & visible
        if (it + 1 < ITERS) {          // issue next tile; stays in flight
            #pragma unroll
            for (int k = 0; k < 4; ++k) {
                const size_t go = (size_t)(r0 + 16 * k + 64 * (it + 1)) * 1024 + c4;
                kr[k] = *(const float4*)(kb + go);
                vr[k] = *(const float4*)(vb + go);
            }
        }
        // fragment assembly: 8 independent ds_read_b64
        union UF { uint2v u[2]; short8 s; };
        UF ua, ub, uc, ud;
        ua.u[0] = *(const uint2v*)(lbase + 0);        // ka0 (d=col)
        ua.u[1] = *(const uint2v*)(lbase + 8);
        ub.u[0] = *(const uint2v*)(lbase + 4352);     // ka1 (d=col+32)
        ub.u[1] = *(const uint2v*)(lbase + 4360);
        uc.u[0] = *(const uint2v*)(lbase + 8704);     // va0 (m=col)
        uc.u[1] = *(const uint2v*)(lbase + 8712);
        ud.u[0] = *(const uint2v*)(lbase + 13056);    // va1 (m=col+32)
        ud.u[1] = *(const uint2v*)(lbase + 13064);
        acc[0][0] = __builtin_amdgcn_mfma_f32_32x32x16_bf16(ua.s, uc.s, acc[0][0], 0, 0, 0);
        acc[0][1] = __builtin_amdgcn_mfma_f32_32x32x16_bf16(ua.s, ud.s, acc[0][1], 0, 0, 0);
        acc[1][0] = __builtin_amdgcn_mfma_f32_32x32x16_bf16(ub.s, uc.s, acc[1][0], 0, 0, 0);
        acc[1][1] = __builtin_amdgcn_mfma_f32_32x32x16_bf16(ub.s, ud.s, acc[1][1], 0, 0, 0);
    }

    // ---- ksum block reduce (thread covered cols c4..c4+3 of its rows)
    BAR();
    *(float4*)&cmb[r0 * 64 + c4] = ks4;
    BAR();
    if (t < 64) {
        float s = 0.f;
        #pragma unroll
        for (int r = 0; r < 16; ++r) s += cmb[r * 64 + t];
        pks[((size_t)chunk * 64 + nh) * 64 + t] = s;
    }

    // ---- acc tree-combine: 2 phases over td, ONE 16KB buffer (R20-proven)
    float* pb = pkv + ((size_t)chunk * 64 + nh) * 4096;
#define FW(BUF, TD)                                                        \
    { _Pragma("unroll") for (int tm = 0; tm < 2; ++tm)                     \
      _Pragma("unroll") for (int r = 0; r < 16; ++r)                       \
          (BUF)[(tm * 16 + r) * 64 + l] = acc[TD][tm][r]; }
#define FR(BUF, TD)                                                        \
    { _Pragma("unroll") for (int tm = 0; tm < 2; ++tm)                     \
      _Pragma("unroll") for (int r = 0; r < 16; ++r)                       \
          acc[TD][tm][r] += (BUF)[(tm * 16 + r) * 64 + l]; }
    #pragma unroll
    for (int td = 0; td < 2; ++td) {
        BAR();   // prior phase's reads (or ksum reads) done
        if (wv == 2) FW(&cmb[0], td);
        if (wv == 3) FW(&cmb[2048], td);
        BAR();
        if (wv == 0) FR(&cmb[0], td);
        if (wv == 1) FR(&cmb[2048], td);
        BAR();
        if (wv == 1) FW(&cmb[0], td);
        BAR();
        if (wv == 0) {
            FR(&cmb[0], td);
            #pragma unroll
            for (int tm = 0; tm < 2; ++tm)
                #pragma unroll
                for (int r = 0; r < 16; ++r) {
                    const int d = 32 * td + (r & 3) + 8 * (r >> 2) + 4 * half;
                    pb[(size_t)d * 64 + 32 * tm + col] = acc[td][tm][r];
                }
        }
    }
#undef FW
#undef FR
}

// ---------------------------------------------------------------------------
// Reduce: kvt[nh][d][m] = sum_c pkv[c][nh][d][m];  ksum[nh][d] = sum_c pks.
// (pkv already in final [d][m] order -> contiguous float4 writes.)
// ---------------------------------------------------------------------------
__global__ __launch_bounds__(256) void kv_reduce_kernel(
    const float* __restrict__ pkv, const float* __restrict__ pks,
    float* __restrict__ kvt, float* __restrict__ ksum, int CH)
{
    const int nh = blockIdx.x;
    const int f4 = blockIdx.y * 256 + threadIdx.x;   // float4 slot 0..1023
    float4 s4 = make_float4(0.f, 0.f, 0.f, 0.f);
    #pragma unroll 4
    for (int c = 0; c < CH; ++c) {
        const float4 v = *(const float4*)(pkv + ((size_t)c * 64 + nh) * 4096 + f4 * 4);
        s4.x += v.x; s4.y += v.y; s4.z += v.z; s4.w += v.w;
    }
    *(float4*)(kvt + (size_t)nh * 4096 + f4 * 4) = s4;

    if (blockIdx.y == 0 && threadIdx.x < 64) {
        float s = 0.f;
        #pragma unroll 4
        for (int c = 0; c < CH; ++c)
            s += pks[((size_t)c * 64 + nh) * 64 + threadIdx.x];
        ksum[nh * 64 + threadIdx.x] = s;
    }
}

// ---------------------------------------------------------------------------
// Phase 2: out[n,l,h,m] = z_l * sum_d Q'[l,d] * KVT[d,m],
//          z_l = 1/(sum_d Q'[l,d]*Ksum[d] + EPS)   (R8 version, ~floor)
// ---------------------------------------------------------------------------
__global__ __launch_bounds__(256) void out_kernel(
    const float* __restrict__ queries, const float* __restrict__ kvt,
    const float* __restrict__ ksum, float* __restrict__ out)
{
    __shared__ float Qs[64][68];    // [l][d]
    __shared__ float KVs[64][68];   // [d][m]
    __shared__ float Ksm[64];

    const int nh = blockIdx.x;
    const int n = nh >> 4, h = nh & 15;
    const int t = threadIdx.x;
    const int l0 = blockIdx.y * 64;

    #pragma unroll
    for (int k = 0; k < 4; ++k) {
        const int idx = t + k * 256;
        *(float4*)&KVs[idx >> 4][(idx & 15) * 4] =
            *(const float4*)(kvt + (size_t)nh * 4096 + idx * 4);
    }
    if (t < 64) Ksm[t] = ksum[nh * 64 + t];

    #pragma unroll
    for (int k = 0; k < 4; ++k) {
        const int idx = t + k * 256;
        const int row = idx >> 4, seg = idx & 15;
        const size_t g = ((size_t)(n * 4096 + l0 + row) * 16 + h) * 64 + seg * 4;
        float4 q4 = *(const float4*)(queries + g);
        q4.x = elu1(q4.x);
        q4.y = elu1(q4.y);
        q4.z = elu1(q4.z);
        q4.w = elu1(q4.w);
        *(float4*)&Qs[row][seg * 4] = q4;
    }
    __syncthreads();

    const int mg = t & 7;          // m cols 4mg..+3 and 32+4mg..+3
    const int lg = t >> 3;         // 0..31; rows lg, lg+32

    float acc[2][8];
    float zacc[2] = {0.f, 0.f};
    #pragma unroll
    for (int i = 0; i < 2; ++i)
        #pragma unroll
        for (int j = 0; j < 8; ++j) acc[i][j] = 0.f;

    #pragma unroll 4
    for (int d0 = 0; d0 < 64; d0 += 4) {
        const float4 km4 = *(const float4*)&Ksm[d0];
        float4 q[2];
        q[0] = *(const float4*)&Qs[lg][d0];
        q[1] = *(const float4*)&Qs[lg + 32][d0];
        #pragma unroll
        for (int i = 0; i < 2; ++i)
            zacc[i] += q[i].x * km4.x + q[i].y * km4.y +
                       q[i].z * km4.z + q[i].w * km4.w;
        #pragma unroll
        for (int r = 0; r < 4; ++r) {
            const float4 kva = *(const float4*)&KVs[d0 + r][mg * 4];
            const float4 kvb = *(const float4*)&KVs[d0 + r][32 + mg * 4];
            #pragma unroll
            for (int i = 0; i < 2; ++i) {
                const float qc = fidx(q[i], r);
                acc[i][0] = fmaf(qc, kva.x, acc[i][0]);
                acc[i][1] = fmaf(qc, kva.y, acc[i][1]);
                acc[i][2] = fmaf(qc, kva.z, acc[i][2]);
                acc[i][3] = fmaf(qc, kva.w, acc[i][3]);
                acc[i][4] = fmaf(qc, kvb.x, acc[i][4]);
                acc[i][5] = fmaf(qc, kvb.y, acc[i][5]);
                acc[i][6] = fmaf(qc, kvb.z, acc[i][6]);
                acc[i][7] = fmaf(qc, kvb.w, acc[i][7]);
            }
        }
    }

    #pragma unroll
    for (int i = 0; i < 2; ++i) {
        const float z = 1.f / (zacc[i] + EPS);
        const int row = l0 + lg + 32 * i;
        const size_t g = ((size_t)(n * 4096 + row) * 16 + h) * 64;
        float4 o;
        o.x = acc[i][0] * z; o.y = acc[i][1] * z;
        o.z = acc[i][2] * z; o.w = acc[i][3] * z;
        *(float4*)(out + g + mg * 4) = o;
        o.x = acc[i][4] * z; o.y = acc[i][5] * z;
        o.z = acc[i][6] * z; o.w = acc[i][7] * z;
        *(float4*)(out + g + 32 + mg * 4) = o;
    }
}

extern "C" void kernel_launch(void* const* d_in, const int* in_sizes, int n_in,
                              void* d_out, int out_size, void* d_ws, size_t ws_size,
                              hipStream_t stream) {
    const float* queries = (const float*)d_in[0];
    const float* keys    = (const float*)d_in[1];
    const float* values  = (const float*)d_in[2];
    const float* mask    = (const float*)d_in[3];
    float* out = (float*)d_out;

    const int CH = 8;   // ~9MB workspace (fits; R1 used 18MB)

    float* pkv  = (float*)d_ws;                      // [8][64][4096] (d,m)
    float* pks  = pkv + (size_t)CH * 64 * 4096;      // [8][64][64]
    float* kvt  = pks + (size_t)CH * 64 * 64;        // [64][4096]
    float* ksum = kvt + (size_t)64 * 4096;           // [64][64]

    kv_partial_kernel<8><<<dim3(64, CH), 256, 0, stream>>>(keys, values, mask,
                                                           pkv, pks);
    kv_reduce_kernel<<<dim3(64, 4), 256, 0, stream>>>(pkv, pks, kvt, ksum, CH);
    out_kernel<<<dim3(64, 64), 256, 0, stream>>>(queries, kvt, ksum, out);
}